// Round 14
// baseline (2137.405 us; speedup 1.0000x reference)
//
#include <hip/hip_runtime.h>
#include <math.h>

// ---------------------------------------------------------------------------
// B=2, S=4096, C=1024, H=16, Dh=64, G=3, Ms=256, NRF=256, L=64
// Round 14: R13 + (1) all prep fused into one launch, (2) vt+nystrom merged
// (independent kernels co-scheduled), (3) gemm launch_bounds (256,4)->(256,5)
// (32KB LDS x5 = 160KB exactly; VGPR 64 fits).
// ---------------------------------------------------------------------------

using f32x4 = __attribute__((ext_vector_type(4))) float;
using s16x8 = __attribute__((ext_vector_type(8))) short;

__device__ __forceinline__ unsigned short f2bf(float x) {
  unsigned u = __float_as_uint(x);
  unsigned r = u + 0x7fffu + ((u >> 16) & 1u);
  return (unsigned short)(r >> 16);
}
__device__ __forceinline__ float bf2f(unsigned short h) {
  return __uint_as_float(((unsigned)h) << 16);
}

// async global -> LDS, 16B per lane; lds dst is wave-uniform base + lane*16
__device__ __forceinline__ void gload16(const void* g, void* l) {
  __builtin_amdgcn_global_load_lds(
      (const __attribute__((address_space(1))) void*)g,
      (__attribute__((address_space(3))) void*)l, 16, 0, 0);
}

// ======================== unified prep ======================================
// fid<4096: x->hi/lo | <4160: omegaT | <4672: rope tab | else weight transp:
//   [4672,5248) conv | [5248,5824) rff | [5824,6400) proj | [6400,6656) outw
__global__ __launch_bounds__(256) void prep_all_kernel(
    const float* __restrict__ x, unsigned short* __restrict__ xhi,
    unsigned short* __restrict__ xlo,
    const float* __restrict__ omega, unsigned short* __restrict__ oThi,
    float2* __restrict__ tab,
    const float* __restrict__ conv_k, const float* __restrict__ rff_w,
    const float* __restrict__ proj_w, const float* __restrict__ out_w,
    unsigned short* __restrict__ Wc_hi, unsigned short* __restrict__ Wc_lo,
    unsigned short* __restrict__ Wr_hi, unsigned short* __restrict__ Wr_lo,
    unsigned short* __restrict__ Wp, unsigned short* __restrict__ Wo)
{
  __shared__ float t[64][65];
  const int fid = blockIdx.x, tid = threadIdx.x;
  if (fid < 4096) {
    const int i = fid * 256 + tid;
    const float4 f0 = ((const float4*)x)[i * 2];
    const float4 f1 = ((const float4*)x)[i * 2 + 1];
    const float v[8] = {f0.x, f0.y, f0.z, f0.w, f1.x, f1.y, f1.z, f1.w};
    s16x8 hi, lo;
    #pragma unroll
    for (int u = 0; u < 8; ++u) {
      const unsigned short hh = f2bf(v[u]);
      hi[u] = (short)hh;
      lo[u] = (short)f2bf(v[u] - bf2f(hh));
    }
    ((s16x8*)xhi)[i] = hi;
    ((s16x8*)xlo)[i] = lo;
    return;
  }
  if (fid < 4160) {
    const int idx = (fid - 4096) * 256 + tid;
    const int m = idx >> 6, d = idx & 63;
    oThi[idx] = f2bf(omega[d * 256 + m]);
    return;
  }
  if (fid < 4672) {
    const int idx = (fid - 4160) * 256 + tid;
    const int j = idx & 31, s = idx >> 5;
    const double inv = pow(10000.0, -(double)j * (1.0 / 32.0));
    double sd, cd;
    sincos((double)s * inv, &sd, &cd);
    tab[idx] = make_float2((float)cd, (float)sd);
    return;
  }
  // ---- weight transpose ----
  const int wfid = fid - 4672;
  const float* in;
  unsigned short *oh, *ol = nullptr;
  int K, N, k0, n0;
  if (wfid < 576) {
    const int z = wfid / 192, r = wfid % 192;
    K = 768; N = 1024; k0 = (r % 12) * 64; n0 = (r / 12) * 64;
    in = conv_k + (size_t)z * 786432;
    oh = Wc_hi + (size_t)z * 786432; ol = Wc_lo + (size_t)z * 786432;
  } else if (wfid < 1152) {
    const int q = wfid - 576;
    const int zz = q / 64, r = q % 64;
    K = 1024; N = 256; k0 = (r % 16) * 64; n0 = (r / 16) * 64;
    const int i = zz / 3, g = zz % 3;
    const size_t off = (size_t)i * 786432 + (size_t)g * 262144;
    in = rff_w + off; oh = Wr_hi + off; ol = Wr_lo + off;
  } else if (wfid < 1728) {
    const int q = wfid - 1152;
    const int z = q / 192, r = q % 192;
    K = 768; N = 1024; k0 = (r % 12) * 64; n0 = (r / 12) * 64;
    in = proj_w + (size_t)z * 786432; oh = Wp + (size_t)z * 786432;
  } else {
    const int q = wfid - 1728;
    K = 1024; N = 1024; k0 = (q % 16) * 64; n0 = (q / 16) * 64;
    in = out_w; oh = Wo;
  }
  const int tn = tid & 63, tr = tid >> 6;
  #pragma unroll 4
  for (int p = 0; p < 16; ++p) {
    const int kk = p * 4 + tr;
    t[kk][tn] = in[(size_t)(k0 + kk) * N + n0 + tn];
  }
  __syncthreads();
  #pragma unroll 4
  for (int p = 0; p < 16; ++p) {
    const int nn = p * 4 + tr;
    const float v = t[tn][nn];
    const unsigned short hi = f2bf(v);
    oh[(size_t)(n0 + nn) * K + k0 + tn] = hi;
    if (ol) ol[(size_t)(n0 + nn) * K + k0 + tn] = f2bf(v - bf2f(hi));
  }
}

// ======================== merged VT + nystrom ===============================
// fid<2048: V bf16 -> VT[bh][80][4096] (+ksum/zero rows); else nystrom MFMA.
__global__ __launch_bounds__(256) void vtny_kernel(
    const unsigned short* __restrict__ V, unsigned short* __restrict__ VT,
    const unsigned short* __restrict__ Kb, const float* __restrict__ lm,
    unsigned short* __restrict__ kny, float* __restrict__ knorm)
{
  __shared__ unsigned tt[64][65];
  __shared__ float lnorm[64];
  const int tid = threadIdx.x;
  if (blockIdx.x < 2048) {
    const int bh = blockIdx.x >> 6, sb = blockIdx.x & 63;
    const int b = bh >> 4, h = bh & 15;
    const int tn = tid & 63, tr = tid >> 6;
    #pragma unroll 4
    for (int p = 0; p < 16; ++p)
      tt[p * 4 + tr][tn] =
          V[(size_t)(b * 4096 + sb * 64 + p * 4 + tr) * 1024 + h * 64 + tn];
    __syncthreads();
    #pragma unroll 4
    for (int p = 0; p < 16; ++p)
      VT[((size_t)bh * 80 + p * 4 + tr) * 4096 + sb * 64 + tn] =
          (unsigned short)tt[tn][p * 4 + tr];
    #pragma unroll
    for (int p = 0; p < 4; ++p) {
      const int rr = p * 4 + tr;
      VT[((size_t)bh * 80 + 64 + rr) * 4096 + sb * 64 + tn] =
          (rr == 0) ? 0x3F80 : 0;
    }
    return;
  }
  // ---- nystrom ----
  const int bid = blockIdx.x - 2048;
  const int bh = bid >> 4, chunk = bid & 15;
  const int b = bh >> 4, h = bh & 15;
  const int lane = tid & 63, wid = tid >> 6;
  const int fr = lane & 15, kc = lane >> 4;
  const int ws0 = chunk * 256 + wid * 64;

  if (tid < 64) {
    float s = 0.f;
    #pragma unroll
    for (int d = 0; d < 64; ++d) { const float v = lm[tid * 64 + d]; s = fmaf(v, v, s); }
    lnorm[tid] = s;
  }
  __syncthreads();

  s16x8 bfr[4][2];
  #pragma unroll
  for (int c = 0; c < 4; ++c)
    #pragma unroll
    for (int ks = 0; ks < 2; ++ks) {
      const float* lp = lm + (c * 16 + fr) * 64 + ks * 32 + kc * 8;
      #pragma unroll
      for (int u = 0; u < 8; ++u) bfr[c][ks][u] = (short)f2bf(lp[u]);
    }

  #pragma unroll
  for (int r = 0; r < 4; ++r) {
    const int s_r = ws0 + r * 16 + fr;
    const unsigned short* ap = Kb + ((size_t)(b * 4096 + s_r)) * 1024 + h * 64;
    s16x8 afr[2];
    float part = 0.f;
    #pragma unroll
    for (int ks = 0; ks < 2; ++ks) {
      afr[ks] = *(const s16x8*)(ap + ks * 32 + kc * 8);
      #pragma unroll
      for (int u = 0; u < 8; ++u) {
        const float v = bf2f((unsigned short)afr[ks][u]);
        part = fmaf(v, v, part);
      }
    }
    part += __shfl_xor(part, 16);
    part += __shfl_xor(part, 32);

    float sq[4] = {0.f, 0.f, 0.f, 0.f};
    #pragma unroll
    for (int c = 0; c < 4; ++c) {
      f32x4 acc = f32x4{0.f, 0.f, 0.f, 0.f};
      acc = __builtin_amdgcn_mfma_f32_16x16x32_bf16(afr[0], bfr[c][0], acc, 0, 0, 0);
      acc = __builtin_amdgcn_mfma_f32_16x16x32_bf16(afr[1], bfr[c][1], acc, 0, 0, 0);
      const float ln = lnorm[c * 16 + fr];
      #pragma unroll
      for (int reg = 0; reg < 4; ++reg) {
        const float nk = __shfl(part, kc * 4 + reg);
        const float val = __expf((2.f * acc[reg] - nk - ln) * 0.015625f);
        sq[reg] = fmaf(val, val, sq[reg]);
        const int srow = ws0 + r * 16 + kc * 4 + reg;
        kny[((size_t)(b * 4096 + srow) * 16 + h) * 64 + c * 16 + fr] = f2bf(val);
      }
    }
    #pragma unroll
    for (int reg = 0; reg < 4; ++reg) {
      float s2 = sq[reg];
      s2 += __shfl_xor(s2, 1); s2 += __shfl_xor(s2, 2);
      s2 += __shfl_xor(s2, 4); s2 += __shfl_xor(s2, 8);
      if (fr == 0) {
        const int srow = ws0 + r * 16 + kc * 4 + reg;
        knorm[(size_t)(b * 4096 + srow) * 16 + h] = 0.5f * s2;
      }
    }
  }
}

// ======================== MFMA GEMM (XCD-swizzled) ==========================
// 128x128 tile, BK=32, 256 threads (2x2 waves), 16x16x32 bf16 MFMA.
// SPLIT modes (0,1): single-buffer loop. PLAIN modes (2,3): double-buffered.
// MODE 2 writes QKV as bf16 (C1) with fused RoPE for z<2.
template<int MODE>
__global__ __launch_bounds__(256, 5) void gemm_mfma(
    const unsigned short* __restrict__ Ahi, const unsigned short* __restrict__ Alo,
    const unsigned short* __restrict__ Bhig, const unsigned short* __restrict__ Blog,
    const float* __restrict__ bias, const float2* __restrict__ tab,
    float* __restrict__ Cf, unsigned short* __restrict__ C1,
    unsigned short* __restrict__ C2,
    int M, int N, int K)
{
  constexpr bool SPLIT = (MODE <= 1);
  __shared__ alignas(16) char smem[32768];
  char* const sAhi = smem;
  char* const sAlo = smem + 8192;
  char* const sBhi = smem + (SPLIT ? 16384 : 8192);
  char* const sBlo = smem + 24576;

  // ---- XCD chunked remap (bijective; nwg % 8 == 0 for all grids) ----
  const int gx = gridDim.x, gy = gridDim.y;
  const int L = blockIdx.x + gx * (blockIdx.y + gy * blockIdx.z);
  const int nwg = gx * gy * gridDim.z;
  const int logical = (L & 7) * (nwg >> 3) + (L >> 3);
  const int bx = logical % gx;
  const int by = (logical / gx) % gy;
  const int z = logical / (gx * gy);

  if constexpr (MODE == 0) {
    Bhig += (size_t)z * 786432; Blog += (size_t)z * 786432;
    bias += z * 1024;
    C1 += (size_t)z * 8388608; C2 += (size_t)z * 8388608;
  } else if constexpr (MODE == 1) {
    Ahi += (size_t)z * 8388608; Alo += (size_t)z * 8388608;
    Bhig += (size_t)z * 786432; Blog += (size_t)z * 786432;
    bias += z * 768;
    C1 += (size_t)z * 6291456;
  } else if constexpr (MODE == 2) {
    Ahi += (size_t)z * 6291456;
    Bhig += (size_t)z * 786432;
    bias += z * 1024;
    C1 += (size_t)z * 8388608;
  }

  const int tid = threadIdx.x;
  const int n0 = bx * 128;
  const int m0 = by * 128;

  const int lane = tid & 63, wid = tid >> 6;
  const int wr = wid >> 1, wc = wid & 1;
  const int fr = lane & 15, kc = lane >> 4;
  const int fsw = ((fr >> 1) & 3) << 4;

  // DMA staging geometry (R8)
  const int seg0 = wid * 2;
  const int r0 = seg0 * 16 + (lane >> 2);
  const int r1 = r0 + 16;
  const int cp = lane & 3;
  const int c0e = (cp ^ ((r0 >> 1) & 3)) * 8;
  const int c1e = (cp ^ ((r1 >> 1) & 3)) * 8;

  f32x4 acc[4][4];
  #pragma unroll
  for (int i = 0; i < 4; ++i)
    #pragma unroll
    for (int j = 0; j < 4; ++j) acc[i][j] = f32x4{0.f, 0.f, 0.f, 0.f};

  if constexpr (SPLIT) {
    char* const dA0 = sAhi + seg0 * 1024;  char* const dA1 = dA0 + 1024;
    char* const dL0 = sAlo + seg0 * 1024;  char* const dL1 = dL0 + 1024;
    char* const dB0 = sBhi + seg0 * 1024;  char* const dB1 = dB0 + 1024;
    char* const dBl0 = sBlo + seg0 * 1024; char* const dBl1 = dBl0 + 1024;

    for (int k0 = 0; k0 < K; k0 += 32) {
      __syncthreads();   // WAR: prior tile's ds_reads complete before DMA lands
      if constexpr (MODE == 0) {
        const int t = k0 >> 8;
        const int cb = (n0 >> 8) * 256 + (k0 & 255);
        const int g0 = m0 + r0, g1 = m0 + r1;
        int s0 = (g0 & 4095) + t - 1; s0 = s0 < 0 ? 0 : (s0 > 4095 ? 4095 : s0);
        int s1 = (g1 & 4095) + t - 1; s1 = s1 < 0 ? 0 : (s1 > 4095 ? 4095 : s1);
        const size_t o0 = ((size_t)((g0 >> 12) * 4096 + s0)) * 1024 + cb;
        const size_t o1 = ((size_t)((g1 >> 12) * 4096 + s1)) * 1024 + cb;
        gload16(Ahi + o0 + c0e, dA0);
        gload16(Ahi + o1 + c1e, dA1);
        gload16(Alo + o0 + c0e, dL0);
        gload16(Alo + o1 + c1e, dL1);
      } else {
        const size_t o0 = (size_t)(m0 + r0) * K + k0;
        const size_t o1 = (size_t)(m0 + r1) * K + k0;
        gload16(Ahi + o0 + c0e, dA0);
        gload16(Ahi + o1 + c1e, dA1);
        gload16(Alo + o0 + c0e, dL0);
        gload16(Alo + o1 + c1e, dL1);
      }
      {
        const size_t o0 = (size_t)(n0 + r0) * K + k0;
        const size_t o1 = (size_t)(n0 + r1) * K + k0;
        gload16(Bhig + o0 + c0e, dB0);
        gload16(Bhig + o1 + c1e, dB1);
        gload16(Blog + o0 + c0e, dBl0);
        gload16(Blog + o1 + c1e, dBl1);
      }
      __syncthreads();   // drains vmcnt(0): tile staged

      if constexpr (MODE == 0) {
        const int t = k0 >> 8;
        int zr = -1;
        if (t == 0 && (m0 & 4095) == 0) zr = 0;
        if (t == 2 && (m0 & 4095) == 3968) zr = 127;
        if (zr >= 0) {
          if (tid < 8) {
            char* buf = (tid < 4) ? sAhi : sAlo;
            *(s16x8*)(buf + zr * 64 + (tid & 3) * 16) = s16x8{0,0,0,0,0,0,0,0};
          }
          __syncthreads();
        }
      }

      s16x8 Af[4], Al[4], Bf[4], Bl[4];
      #pragma unroll
      for (int i = 0; i < 4; ++i) {
        const int off = (wr * 64 + i * 16 + fr) * 64 + ((kc * 16) ^ fsw);
        Af[i] = *(const s16x8*)(sAhi + off);
        Al[i] = *(const s16x8*)(sAlo + off);
      }
      #pragma unroll
      for (int j = 0; j < 4; ++j) {
        const int off = (wc * 64 + j * 16 + fr) * 64 + ((kc * 16) ^ fsw);
        Bf[j] = *(const s16x8*)(sBhi + off);
        Bl[j] = *(const s16x8*)(sBlo + off);
      }
      #pragma unroll
      for (int i = 0; i < 4; ++i)
        #pragma unroll
        for (int j = 0; j < 4; ++j) {
          acc[i][j] = __builtin_amdgcn_mfma_f32_16x16x32_bf16(Af[i], Bf[j], acc[i][j], 0, 0, 0);
          acc[i][j] = __builtin_amdgcn_mfma_f32_16x16x32_bf16(Af[i], Bl[j], acc[i][j], 0, 0, 0);
          acc[i][j] = __builtin_amdgcn_mfma_f32_16x16x32_bf16(Al[i], Bf[j], acc[i][j], 0, 0, 0);
        }
    }
  } else {
    // double-buffered loop (plain modes): buffer p at {p*16384, p*16384+8192}
    auto stagep = [&](int k0, int par) {
      char* const bA = smem + par * 16384;
      char* const bB = bA + 8192;
      const size_t o0 = (size_t)(m0 + r0) * K + k0;
      const size_t o1 = (size_t)(m0 + r1) * K + k0;
      gload16(Ahi + o0 + c0e, bA + seg0 * 1024);
      gload16(Ahi + o1 + c1e, bA + seg0 * 1024 + 1024);
      const size_t b0 = (size_t)(n0 + r0) * K + k0;
      const size_t b1 = (size_t)(n0 + r1) * K + k0;
      gload16(Bhig + b0 + c0e, bB + seg0 * 1024);
      gload16(Bhig + b1 + c1e, bB + seg0 * 1024 + 1024);
    };
    stagep(0, 0);
    __syncthreads();                 // tile 0 landed
    for (int k0 = 0; k0 < K; k0 += 32) {
      const int cur = (k0 >> 5) & 1;
      if (k0 + 32 < K) stagep(k0 + 32, cur ^ 1);   // next tile streams in
      const char* bA = smem + cur * 16384;
      const char* bB = bA + 8192;
      s16x8 Af[4], Bf[4];
      #pragma unroll
      for (int i = 0; i < 4; ++i) {
        const int off = (wr * 64 + i * 16 + fr) * 64 + ((kc * 16) ^ fsw);
        Af[i] = *(const s16x8*)(bA + off);
      }
      #pragma unroll
      for (int j = 0; j < 4; ++j) {
        const int off = (wc * 64 + j * 16 + fr) * 64 + ((kc * 16) ^ fsw);
        Bf[j] = *(const s16x8*)(bB + off);
      }
      #pragma unroll
      for (int i = 0; i < 4; ++i)
        #pragma unroll
        for (int j = 0; j < 4; ++j)
          acc[i][j] = __builtin_amdgcn_mfma_f32_16x16x32_bf16(Af[i], Bf[j], acc[i][j], 0, 0, 0);
      __syncthreads();   // drains next-tile DMAs + WAR for buffer reuse
    }
  }

  // ---- epilogue ----
  if constexpr (MODE == 2) {
    #pragma unroll
    for (int i = 0; i < 4; ++i)
      #pragma unroll
      for (int j2 = 0; j2 < 2; ++j2) {
        const int col0 = n0 + wc * 64 + j2 * 16 + fr;
        const int jr = col0 & 31;
        const float b0 = bias[col0], b1 = bias[col0 + 32];
        #pragma unroll
        for (int rr = 0; rr < 4; ++rr) {
          const int row = m0 + wr * 64 + i * 16 + kc * 4 + rr;
          float v0 = acc[i][j2][rr] + b0;
          float v1 = acc[i][j2 + 2][rr] + b1;
          if (z < 2) {
            const float2 cs = tab[((row & 4095) << 5) | jr];
            const float rr0 = v0 * cs.x - v1 * cs.y;
            const float rr1 = v1 * cs.x + v0 * cs.y;
            v0 = rr0; v1 = rr1;
          }
          C1[(size_t)row * N + col0] = f2bf(v0);
          C1[(size_t)row * N + col0 + 32] = f2bf(v1);
        }
      }
  } else {
    #pragma unroll
    for (int i = 0; i < 4; ++i)
      #pragma unroll
      for (int j = 0; j < 4; ++j) {
        const int col = n0 + wc * 64 + j * 16 + fr;
        #pragma unroll
        for (int rr = 0; rr < 4; ++rr) {
          const int row = m0 + wr * 64 + i * 16 + kc * 4 + rr;
          const float v = acc[i][j][rr];
          if constexpr (MODE == 0) {
            const float hv = v + bias[col];
            const unsigned short hh = f2bf(hv);
            C1[(size_t)row * N + col] = hh;
            C2[(size_t)row * N + col] = f2bf(hv - bf2f(hh));
          } else if constexpr (MODE == 1) {
            const int g = col >> 8;
            const float sg = (g == 0) ? 1.0f : ((g == 1) ? 1.41421356237309515f : 2.0f);
            const float zc = cosf(v * sg + bias[col]) * 0.08838834764831845f;
            C1[(size_t)row * N + col] = f2bf(zc);
          } else {
            Cf[(size_t)row * N + col] = v + bias[col];
          }
        }
      }
  }
}

// ======================== FAVOR-K (MFMA, single-term) =======================
__global__ __launch_bounds__(512) void favor_k_mfma(
    const unsigned short* __restrict__ kny, const float* __restrict__ knorm,
    const unsigned short* __restrict__ oThi,
    const unsigned short* __restrict__ VT, float* __restrict__ KVp)
{
  const int bid = blockIdx.x;
  const int bh = bid >> 3, chunk = bid & 7;
  const int b = bh >> 4, h = bh & 15;
  const int s0 = chunk * 512;
  const int tid = threadIdx.x, lane = tid & 63, wid = tid >> 6;
  const int fr = lane & 15, kc = lane >> 4;
  const int m0w = wid * 32;

  __shared__ unsigned short P[256][40];
  __shared__ float T[8][32][84];

  s16x8 whi[2][2];
  #pragma unroll
  for (int c = 0; c < 2; ++c)
    #pragma unroll
    for (int ks = 0; ks < 2; ++ks)
      whi[c][ks] = *(const s16x8*)(oThi + (size_t)(m0w + c * 16 + fr) * 64 + ks * 32 + kc * 8);

  f32x4 acc2[2][5];
  #pragma unroll
  for (int i = 0; i < 2; ++i)
    #pragma unroll
    for (int j = 0; j < 5; ++j) acc2[i][j] = f32x4{0.f, 0.f, 0.f, 0.f};

  for (int st = 0; st < 512; st += 32) {
    s16x8 a1[2][2];
    float nrm[2];
    #pragma unroll
    for (int r = 0; r < 2; ++r) {
      const size_t kidx = (size_t)(b * 4096 + s0 + st + r * 16 + fr) * 16 + h;
      a1[r][0] = *(const s16x8*)(kny + kidx * 64 + kc * 8);
      a1[r][1] = *(const s16x8*)(kny + kidx * 64 + 32 + kc * 8);
      nrm[r] = knorm[kidx];
    }
    __syncthreads();
    #pragma unroll
    for (int r = 0; r < 2; ++r)
      #pragma unroll
      for (int c = 0; c < 2; ++c) {
        f32x4 s1 = f32x4{0.f, 0.f, 0.f, 0.f};
        s1 = __builtin_amdgcn_mfma_f32_16x16x32_bf16(a1[r][0], whi[c][0], s1, 0, 0, 0);
        s1 = __builtin_amdgcn_mfma_f32_16x16x32_bf16(a1[r][1], whi[c][1], s1, 0, 0, 0);
        #pragma unroll
        for (int reg = 0; reg < 4; ++reg) {
          const int sl = kc * 4 + reg;
          const float nn = __shfl(nrm[r], sl);
          const float p = __expf(s1[reg] - nn - 2.772588722239781f);
          P[m0w + c * 16 + fr][r * 16 + sl] = f2bf(p);
        }
      }
    __syncthreads();
    s16x8 b2[5];
    #pragma unroll
    for (int nf = 0; nf < 5; ++nf)
      b2[nf] = *(const s16x8*)(VT + ((size_t)bh * 80 + nf * 16 + fr) * 4096 +
                               s0 + st + kc * 8);
    #pragma unroll
    for (int mf = 0; mf < 2; ++mf) {
      const s16x8 a2 = *(const s16x8*)&P[m0w + mf * 16 + fr][kc * 8];
      #pragma unroll
      for (int nf = 0; nf < 5; ++nf)
        acc2[mf][nf] = __builtin_amdgcn_mfma_f32_16x16x32_bf16(a2, b2[nf], acc2[mf][nf], 0, 0, 0);
    }
  }
  #pragma unroll
  for (int mf = 0; mf < 2; ++mf)
    #pragma unroll
    for (int nf = 0; nf < 5; ++nf)
      #pragma unroll
      for (int reg = 0; reg < 4; ++reg)
        T[wid][mf * 16 + kc * 4 + reg][nf * 16 + fr] = acc2[mf][nf][reg];
  __syncthreads();
  #pragma unroll
  for (int i = 0; i < 40; ++i) {
    const int flat = i * 64 + lane;
    const int n = flat >> 5, ml = flat & 31;
    KVp[((size_t)bid * 80 + n) * 256 + m0w + ml] = T[wid][ml][n];
  }
}

// ======================== reduce KVp -> KVXT bf16 (widened) =================
__global__ __launch_bounds__(256) void reduce_kvxt_kernel(
    const float* __restrict__ KVp, unsigned short* __restrict__ KVXT)
{
  const int bh = blockIdx.x;
  const int n0 = blockIdx.y * 8;
  const int m = threadIdx.x;
  #pragma unroll
  for (int n = n0; n < n0 + 8; ++n) {
    float s = 0.f;
    #pragma unroll
    for (int c = 0; c < 8; ++c)
      s += KVp[((size_t)(bh * 8 + c) * 80 + n) * 256 + m];
    KVXT[((size_t)bh * 80 + n) * 256 + m] = f2bf(s);
  }
}

// ======================== FAVOR-Q (MFMA, bf16 Q input) ======================
__global__ __launch_bounds__(512) void favor_q_mfma(
    const unsigned short* __restrict__ Q, const unsigned short* __restrict__ oThi,
    const unsigned short* __restrict__ KVXT, unsigned short* __restrict__ O)
{
  const int bid = blockIdx.x;
  const int bh = bid >> 4, chunk = bid & 15;
  const int b = bh >> 4, h = bh & 15;
  const int s0 = chunk * 256;
  const int tid = threadIdx.x, lane = tid & 63, wid = tid >> 6;
  const int fr = lane & 15, kc = lane >> 4;
  const int ws0 = s0 + wid * 32;

  __shared__ unsigned short KX[80][264];
  __shared__ unsigned short P[8][32][66];

  for (int i = tid; i < 80 * 256; i += 512)
    KX[i >> 8][i & 255] = KVXT[(size_t)bh * 80 * 256 + i];
  __syncthreads();

  s16x8 ahi[2][2];
  float nrm[2];
  #pragma unroll
  for (int r = 0; r < 2; ++r) {
    float part = 0.f;
    const unsigned short* ap = Q + ((size_t)(b * 4096 + ws0 + r * 16 + fr)) * 1024 + h * 64;
    #pragma unroll
    for (int ks = 0; ks < 2; ++ks) {
      ahi[r][ks] = *(const s16x8*)(ap + ks * 32 + kc * 8);
      #pragma unroll
      for (int u = 0; u < 8; ++u) {
        const float v = bf2f((unsigned short)ahi[r][ks][u]);
        part = fmaf(v, v, part);
      }
    }
    part += __shfl_xor(part, 16);
    part += __shfl_xor(part, 32);
    nrm[r] = 0.5f * part;
  }

  f32x4 acc2[2][5];
  #pragma unroll
  for (int i = 0; i < 2; ++i)
    #pragma unroll
    for (int j = 0; j < 5; ++j) acc2[i][j] = f32x4{0.f, 0.f, 0.f, 0.f};

  for (int mc = 0; mc < 4; ++mc) {
    __syncthreads();
    #pragma unroll
    for (int r = 0; r < 2; ++r)
      #pragma unroll
      for (int c = 0; c < 4; ++c) {
        f32x4 s1 = f32x4{0.f, 0.f, 0.f, 0.f};
        #pragma unroll
        for (int ks = 0; ks < 2; ++ks) {
          const size_t off = (size_t)(mc * 64 + c * 16 + fr) * 64 + ks * 32 + kc * 8;
          const s16x8 bh1 = *(const s16x8*)(oThi + off);
          s1 = __builtin_amdgcn_mfma_f32_16x16x32_bf16(ahi[r][ks], bh1, s1, 0, 0, 0);
        }
        #pragma unroll
        for (int reg = 0; reg < 4; ++reg) {
          const int sl = kc * 4 + reg;
          const float nn = __shfl(nrm[r], sl);
          const float p = __expf(s1[reg] - nn - 2.772588722239781f);
          P[wid][r * 16 + sl][c * 16 + fr] = f2bf(p);
        }
      }
    __syncthreads();
    #pragma unroll
    for (int ks2 = 0; ks2 < 2; ++ks2) {
      s16x8 b2[5];
      #pragma unroll
      for (int nf = 0; nf < 5; ++nf)
        b2[nf] = *(const s16x8*)&KX[nf * 16 + fr][mc * 64 + ks2 * 32 + kc * 8];
      #pragma unroll
      for (int r = 0; r < 2; ++r) {
        const s16x8 a2 = *(const s16x8*)&P[wid][r * 16 + fr][ks2 * 32 + kc * 8];
        #pragma unroll
        for (int nf = 0; nf < 5; ++nf)
          acc2[r][nf] = __builtin_amdgcn_mfma_f32_16x16x32_bf16(a2, b2[nf], acc2[r][nf], 0, 0, 0);
      }
    }
  }
  #pragma unroll
  for (int r = 0; r < 2; ++r)
    #pragma unroll
    for (int reg = 0; reg < 4; ++reg) {
      const int s = ws0 + r * 16 + kc * 4 + reg;
      const float dv = __shfl(acc2[r][4][reg], lane & 48) + 1e-6f;
      #pragma unroll
      for (int nf = 0; nf < 4; ++nf)
        O[(size_t)(b * 4096 + s) * 1024 + h * 64 + nf * 16 + fr] =
            f2bf(acc2[r][nf][reg] / dv);
    }
}

// ======================== launcher ==========================================
extern "C" void kernel_launch(void* const* d_in, const int* in_sizes, int n_in,
                              void* d_out, int out_size, void* d_ws, size_t ws_size,
                              hipStream_t stream)
{
  const float* x      = (const float*)d_in[0];
  const float* conv_k = (const float*)d_in[1];
  const float* conv_b = (const float*)d_in[2];
  const float* rff_w  = (const float*)d_in[3];
  const float* rff_b  = (const float*)d_in[4];
  const float* proj_w = (const float*)d_in[5];
  const float* proj_b = (const float*)d_in[6];
  const float* omega  = (const float*)d_in[7];
  const float* lm     = (const float*)d_in[8];
  const float* out_w  = (const float*)d_in[9];
  const float* out_b  = (const float*)d_in[10];

  char* wsb = (char*)d_ws;
  size_t o = 0;
  auto alloc = [&](size_t bytes) {
    char* p = wsb + o;
    o = (o + bytes + 255) & ~(size_t)255;
    return p;
  };
  // --- region A: persistent (weights/tables)
  unsigned short* Wc_hi = (unsigned short*)alloc(4718592);
  unsigned short* Wc_lo = (unsigned short*)alloc(4718592);
  unsigned short* Wr_hi = (unsigned short*)alloc(4718592);
  unsigned short* Wr_lo = (unsigned short*)alloc(4718592);
  unsigned short* Wp    = (unsigned short*)alloc(4718592);
  unsigned short* Wo    = (unsigned short*)alloc(2097152);
  unsigned short* oThi  = (unsigned short*)alloc(32768);
  float2* tab           = (float2*)alloc(1048576);
  // --- region B: xhi/xlo -> feats -> {VT, Obf, KVXT}
  char* RB = alloc(41943040);
  unsigned short* xhi   = (unsigned short*)RB;
  unsigned short* xlo   = (unsigned short*)(RB + 16777216);
  unsigned short* feats = (unsigned short*)RB;
  unsigned short* VT    = (unsigned short*)RB;
  unsigned short* Obf   = (unsigned short*)(RB + 20971520);
  unsigned short* KVXT  = (unsigned short*)(RB + 37748736);
  // --- region C: h hi/lo (3x) -> QKV bf16 (3x)
  char* RC = alloc(100663296);
  unsigned short* hhi   = (unsigned short*)RC;
  unsigned short* hlo   = (unsigned short*)(RC + 50331648);
  unsigned short* QKV   = (unsigned short*)RC;            // 48 MB bf16
  // --- region E: kny bf16 + knorm + KVp
  char* RE = alloc(33554432);
  unsigned short* knyb  = (unsigned short*)RE;
  float* knorm          = (float*)(RE + 16777216);
  float* KVp = (float*)alloc(20971520);
  (void)ws_size;

  dim3 blk(256);
  prep_all_kernel<<<6656, blk, 0, stream>>>(
      x, xhi, xlo, omega, oThi, tab,
      conv_k, rff_w, proj_w, out_w,
      Wc_hi, Wc_lo, Wr_hi, Wr_lo, Wp, Wo);

  gemm_mfma<0><<<dim3(8, 64, 3), blk, 0, stream>>>(
      xhi, xlo, Wc_hi, Wc_lo, conv_b, nullptr,
      nullptr, hhi, hlo, 8192, 1024, 768);
  gemm_mfma<1><<<dim3(6, 64, 3), blk, 0, stream>>>(
      hhi, hlo, Wr_hi, Wr_lo, rff_b, nullptr,
      nullptr, feats, nullptr, 8192, 768, 1024);
  gemm_mfma<2><<<dim3(8, 64, 3), blk, 0, stream>>>(
      feats, nullptr, Wp, nullptr, proj_b, tab,
      nullptr, QKV, nullptr, 8192, 1024, 768);

  unsigned short* Qb = QKV;
  unsigned short* Kb = QKV + 8388608;
  unsigned short* Vb = QKV + 16777216;
  vtny_kernel<<<2560, blk, 0, stream>>>(Vb, VT, Kb, lm, knyb, knorm);
  favor_k_mfma<<<256, dim3(512), 0, stream>>>(knyb, knorm, oThi, VT, KVp);
  reduce_kvxt_kernel<<<dim3(32, 10), blk, 0, stream>>>(KVp, KVXT);
  favor_q_mfma<<<512, dim3(512), 0, stream>>>(Qb, oThi, KVXT, Obf);
  gemm_mfma<3><<<dim3(8, 64, 1), blk, 0, stream>>>(
      Obf, nullptr, Wo, nullptr, out_b, nullptr,
      (float*)d_out, nullptr, nullptr, 8192, 1024, 1024);
}

// Round 15
// 872.492 us; speedup vs baseline: 2.4498x; 2.4498x over previous
//
#include <hip/hip_runtime.h>
#include <math.h>

// ---------------------------------------------------------------------------
// B=2, S=4096, C=1024, H=16, Dh=64, G=3, Ms=256, NRF=256, L=64
// Round 15: R14 with gemm launch_bounds reverted (256,5)->(256,4).
// (R14's 48-VGPR cap from min-5-blocks destroyed GEMM codegen: FETCH x4,
// dur x2.6. Prep fusion + vtny merge retained.)
// ---------------------------------------------------------------------------

using f32x4 = __attribute__((ext_vector_type(4))) float;
using s16x8 = __attribute__((ext_vector_type(8))) short;

__device__ __forceinline__ unsigned short f2bf(float x) {
  unsigned u = __float_as_uint(x);
  unsigned r = u + 0x7fffu + ((u >> 16) & 1u);
  return (unsigned short)(r >> 16);
}
__device__ __forceinline__ float bf2f(unsigned short h) {
  return __uint_as_float(((unsigned)h) << 16);
}

// async global -> LDS, 16B per lane; lds dst is wave-uniform base + lane*16
__device__ __forceinline__ void gload16(const void* g, void* l) {
  __builtin_amdgcn_global_load_lds(
      (const __attribute__((address_space(1))) void*)g,
      (__attribute__((address_space(3))) void*)l, 16, 0, 0);
}

// ======================== unified prep ======================================
// fid<4096: x->hi/lo | <4160: omegaT | <4672: rope tab | else weight transp:
//   [4672,5248) conv | [5248,5824) rff | [5824,6400) proj | [6400,6656) outw
__global__ __launch_bounds__(256) void prep_all_kernel(
    const float* __restrict__ x, unsigned short* __restrict__ xhi,
    unsigned short* __restrict__ xlo,
    const float* __restrict__ omega, unsigned short* __restrict__ oThi,
    float2* __restrict__ tab,
    const float* __restrict__ conv_k, const float* __restrict__ rff_w,
    const float* __restrict__ proj_w, const float* __restrict__ out_w,
    unsigned short* __restrict__ Wc_hi, unsigned short* __restrict__ Wc_lo,
    unsigned short* __restrict__ Wr_hi, unsigned short* __restrict__ Wr_lo,
    unsigned short* __restrict__ Wp, unsigned short* __restrict__ Wo)
{
  __shared__ float t[64][65];
  const int fid = blockIdx.x, tid = threadIdx.x;
  if (fid < 4096) {
    const int i = fid * 256 + tid;
    const float4 f0 = ((const float4*)x)[i * 2];
    const float4 f1 = ((const float4*)x)[i * 2 + 1];
    const float v[8] = {f0.x, f0.y, f0.z, f0.w, f1.x, f1.y, f1.z, f1.w};
    s16x8 hi, lo;
    #pragma unroll
    for (int u = 0; u < 8; ++u) {
      const unsigned short hh = f2bf(v[u]);
      hi[u] = (short)hh;
      lo[u] = (short)f2bf(v[u] - bf2f(hh));
    }
    ((s16x8*)xhi)[i] = hi;
    ((s16x8*)xlo)[i] = lo;
    return;
  }
  if (fid < 4160) {
    const int idx = (fid - 4096) * 256 + tid;
    const int m = idx >> 6, d = idx & 63;
    oThi[idx] = f2bf(omega[d * 256 + m]);
    return;
  }
  if (fid < 4672) {
    const int idx = (fid - 4160) * 256 + tid;
    const int j = idx & 31, s = idx >> 5;
    const double inv = pow(10000.0, -(double)j * (1.0 / 32.0));
    double sd, cd;
    sincos((double)s * inv, &sd, &cd);
    tab[idx] = make_float2((float)cd, (float)sd);
    return;
  }
  // ---- weight transpose ----
  const int wfid = fid - 4672;
  const float* in;
  unsigned short *oh, *ol = nullptr;
  int K, N, k0, n0;
  if (wfid < 576) {
    const int z = wfid / 192, r = wfid % 192;
    K = 768; N = 1024; k0 = (r % 12) * 64; n0 = (r / 12) * 64;
    in = conv_k + (size_t)z * 786432;
    oh = Wc_hi + (size_t)z * 786432; ol = Wc_lo + (size_t)z * 786432;
  } else if (wfid < 1152) {
    const int q = wfid - 576;
    const int zz = q / 64, r = q % 64;
    K = 1024; N = 256; k0 = (r % 16) * 64; n0 = (r / 16) * 64;
    const int i = zz / 3, g = zz % 3;
    const size_t off = (size_t)i * 786432 + (size_t)g * 262144;
    in = rff_w + off; oh = Wr_hi + off; ol = Wr_lo + off;
  } else if (wfid < 1728) {
    const int q = wfid - 1152;
    const int z = q / 192, r = q % 192;
    K = 768; N = 1024; k0 = (r % 12) * 64; n0 = (r / 12) * 64;
    in = proj_w + (size_t)z * 786432; oh = Wp + (size_t)z * 786432;
  } else {
    const int q = wfid - 1728;
    K = 1024; N = 1024; k0 = (q % 16) * 64; n0 = (q / 16) * 64;
    in = out_w; oh = Wo;
  }
  const int tn = tid & 63, tr = tid >> 6;
  #pragma unroll 4
  for (int p = 0; p < 16; ++p) {
    const int kk = p * 4 + tr;
    t[kk][tn] = in[(size_t)(k0 + kk) * N + n0 + tn];
  }
  __syncthreads();
  #pragma unroll 4
  for (int p = 0; p < 16; ++p) {
    const int nn = p * 4 + tr;
    const float v = t[tn][nn];
    const unsigned short hi = f2bf(v);
    oh[(size_t)(n0 + nn) * K + k0 + tn] = hi;
    if (ol) ol[(size_t)(n0 + nn) * K + k0 + tn] = f2bf(v - bf2f(hi));
  }
}

// ======================== merged VT + nystrom ===============================
// fid<2048: V bf16 -> VT[bh][80][4096] (+ksum/zero rows); else nystrom MFMA.
__global__ __launch_bounds__(256) void vtny_kernel(
    const unsigned short* __restrict__ V, unsigned short* __restrict__ VT,
    const unsigned short* __restrict__ Kb, const float* __restrict__ lm,
    unsigned short* __restrict__ kny, float* __restrict__ knorm)
{
  __shared__ unsigned tt[64][65];
  __shared__ float lnorm[64];
  const int tid = threadIdx.x;
  if (blockIdx.x < 2048) {
    const int bh = blockIdx.x >> 6, sb = blockIdx.x & 63;
    const int b = bh >> 4, h = bh & 15;
    const int tn = tid & 63, tr = tid >> 6;
    #pragma unroll 4
    for (int p = 0; p < 16; ++p)
      tt[p * 4 + tr][tn] =
          V[(size_t)(b * 4096 + sb * 64 + p * 4 + tr) * 1024 + h * 64 + tn];
    __syncthreads();
    #pragma unroll 4
    for (int p = 0; p < 16; ++p)
      VT[((size_t)bh * 80 + p * 4 + tr) * 4096 + sb * 64 + tn] =
          (unsigned short)tt[tn][p * 4 + tr];
    #pragma unroll
    for (int p = 0; p < 4; ++p) {
      const int rr = p * 4 + tr;
      VT[((size_t)bh * 80 + 64 + rr) * 4096 + sb * 64 + tn] =
          (rr == 0) ? 0x3F80 : 0;
    }
    return;
  }
  // ---- nystrom ----
  const int bid = blockIdx.x - 2048;
  const int bh = bid >> 4, chunk = bid & 15;
  const int b = bh >> 4, h = bh & 15;
  const int lane = tid & 63, wid = tid >> 6;
  const int fr = lane & 15, kc = lane >> 4;
  const int ws0 = chunk * 256 + wid * 64;

  if (tid < 64) {
    float s = 0.f;
    #pragma unroll
    for (int d = 0; d < 64; ++d) { const float v = lm[tid * 64 + d]; s = fmaf(v, v, s); }
    lnorm[tid] = s;
  }
  __syncthreads();

  s16x8 bfr[4][2];
  #pragma unroll
  for (int c = 0; c < 4; ++c)
    #pragma unroll
    for (int ks = 0; ks < 2; ++ks) {
      const float* lp = lm + (c * 16 + fr) * 64 + ks * 32 + kc * 8;
      #pragma unroll
      for (int u = 0; u < 8; ++u) bfr[c][ks][u] = (short)f2bf(lp[u]);
    }

  #pragma unroll
  for (int r = 0; r < 4; ++r) {
    const int s_r = ws0 + r * 16 + fr;
    const unsigned short* ap = Kb + ((size_t)(b * 4096 + s_r)) * 1024 + h * 64;
    s16x8 afr[2];
    float part = 0.f;
    #pragma unroll
    for (int ks = 0; ks < 2; ++ks) {
      afr[ks] = *(const s16x8*)(ap + ks * 32 + kc * 8);
      #pragma unroll
      for (int u = 0; u < 8; ++u) {
        const float v = bf2f((unsigned short)afr[ks][u]);
        part = fmaf(v, v, part);
      }
    }
    part += __shfl_xor(part, 16);
    part += __shfl_xor(part, 32);

    float sq[4] = {0.f, 0.f, 0.f, 0.f};
    #pragma unroll
    for (int c = 0; c < 4; ++c) {
      f32x4 acc = f32x4{0.f, 0.f, 0.f, 0.f};
      acc = __builtin_amdgcn_mfma_f32_16x16x32_bf16(afr[0], bfr[c][0], acc, 0, 0, 0);
      acc = __builtin_amdgcn_mfma_f32_16x16x32_bf16(afr[1], bfr[c][1], acc, 0, 0, 0);
      const float ln = lnorm[c * 16 + fr];
      #pragma unroll
      for (int reg = 0; reg < 4; ++reg) {
        const float nk = __shfl(part, kc * 4 + reg);
        const float val = __expf((2.f * acc[reg] - nk - ln) * 0.015625f);
        sq[reg] = fmaf(val, val, sq[reg]);
        const int srow = ws0 + r * 16 + kc * 4 + reg;
        kny[((size_t)(b * 4096 + srow) * 16 + h) * 64 + c * 16 + fr] = f2bf(val);
      }
    }
    #pragma unroll
    for (int reg = 0; reg < 4; ++reg) {
      float s2 = sq[reg];
      s2 += __shfl_xor(s2, 1); s2 += __shfl_xor(s2, 2);
      s2 += __shfl_xor(s2, 4); s2 += __shfl_xor(s2, 8);
      if (fr == 0) {
        const int srow = ws0 + r * 16 + kc * 4 + reg;
        knorm[(size_t)(b * 4096 + srow) * 16 + h] = 0.5f * s2;
      }
    }
  }
}

// ======================== MFMA GEMM (XCD-swizzled) ==========================
// 128x128 tile, BK=32, 256 threads (2x2 waves), 16x16x32 bf16 MFMA.
// SPLIT modes (0,1): single-buffer loop. PLAIN modes (2,3): double-buffered.
// MODE 2 writes QKV as bf16 (C1) with fused RoPE for z<2.
template<int MODE>
__global__ __launch_bounds__(256, 4) void gemm_mfma(
    const unsigned short* __restrict__ Ahi, const unsigned short* __restrict__ Alo,
    const unsigned short* __restrict__ Bhig, const unsigned short* __restrict__ Blog,
    const float* __restrict__ bias, const float2* __restrict__ tab,
    float* __restrict__ Cf, unsigned short* __restrict__ C1,
    unsigned short* __restrict__ C2,
    int M, int N, int K)
{
  constexpr bool SPLIT = (MODE <= 1);
  __shared__ alignas(16) char smem[32768];
  char* const sAhi = smem;
  char* const sAlo = smem + 8192;
  char* const sBhi = smem + (SPLIT ? 16384 : 8192);
  char* const sBlo = smem + 24576;

  // ---- XCD chunked remap (bijective; nwg % 8 == 0 for all grids) ----
  const int gx = gridDim.x, gy = gridDim.y;
  const int L = blockIdx.x + gx * (blockIdx.y + gy * blockIdx.z);
  const int nwg = gx * gy * gridDim.z;
  const int logical = (L & 7) * (nwg >> 3) + (L >> 3);
  const int bx = logical % gx;
  const int by = (logical / gx) % gy;
  const int z = logical / (gx * gy);

  if constexpr (MODE == 0) {
    Bhig += (size_t)z * 786432; Blog += (size_t)z * 786432;
    bias += z * 1024;
    C1 += (size_t)z * 8388608; C2 += (size_t)z * 8388608;
  } else if constexpr (MODE == 1) {
    Ahi += (size_t)z * 8388608; Alo += (size_t)z * 8388608;
    Bhig += (size_t)z * 786432; Blog += (size_t)z * 786432;
    bias += z * 768;
    C1 += (size_t)z * 6291456;
  } else if constexpr (MODE == 2) {
    Ahi += (size_t)z * 6291456;
    Bhig += (size_t)z * 786432;
    bias += z * 1024;
    C1 += (size_t)z * 8388608;
  }

  const int tid = threadIdx.x;
  const int n0 = bx * 128;
  const int m0 = by * 128;

  const int lane = tid & 63, wid = tid >> 6;
  const int wr = wid >> 1, wc = wid & 1;
  const int fr = lane & 15, kc = lane >> 4;
  const int fsw = ((fr >> 1) & 3) << 4;

  // DMA staging geometry (R8)
  const int seg0 = wid * 2;
  const int r0 = seg0 * 16 + (lane >> 2);
  const int r1 = r0 + 16;
  const int cp = lane & 3;
  const int c0e = (cp ^ ((r0 >> 1) & 3)) * 8;
  const int c1e = (cp ^ ((r1 >> 1) & 3)) * 8;

  f32x4 acc[4][4];
  #pragma unroll
  for (int i = 0; i < 4; ++i)
    #pragma unroll
    for (int j = 0; j < 4; ++j) acc[i][j] = f32x4{0.f, 0.f, 0.f, 0.f};

  if constexpr (SPLIT) {
    char* const dA0 = sAhi + seg0 * 1024;  char* const dA1 = dA0 + 1024;
    char* const dL0 = sAlo + seg0 * 1024;  char* const dL1 = dL0 + 1024;
    char* const dB0 = sBhi + seg0 * 1024;  char* const dB1 = dB0 + 1024;
    char* const dBl0 = sBlo + seg0 * 1024; char* const dBl1 = dBl0 + 1024;

    for (int k0 = 0; k0 < K; k0 += 32) {
      __syncthreads();   // WAR: prior tile's ds_reads complete before DMA lands
      if constexpr (MODE == 0) {
        const int t = k0 >> 8;
        const int cb = (n0 >> 8) * 256 + (k0 & 255);
        const int g0 = m0 + r0, g1 = m0 + r1;
        int s0 = (g0 & 4095) + t - 1; s0 = s0 < 0 ? 0 : (s0 > 4095 ? 4095 : s0);
        int s1 = (g1 & 4095) + t - 1; s1 = s1 < 0 ? 0 : (s1 > 4095 ? 4095 : s1);
        const size_t o0 = ((size_t)((g0 >> 12) * 4096 + s0)) * 1024 + cb;
        const size_t o1 = ((size_t)((g1 >> 12) * 4096 + s1)) * 1024 + cb;
        gload16(Ahi + o0 + c0e, dA0);
        gload16(Ahi + o1 + c1e, dA1);
        gload16(Alo + o0 + c0e, dL0);
        gload16(Alo + o1 + c1e, dL1);
      } else {
        const size_t o0 = (size_t)(m0 + r0) * K + k0;
        const size_t o1 = (size_t)(m0 + r1) * K + k0;
        gload16(Ahi + o0 + c0e, dA0);
        gload16(Ahi + o1 + c1e, dA1);
        gload16(Alo + o0 + c0e, dL0);
        gload16(Alo + o1 + c1e, dL1);
      }
      {
        const size_t o0 = (size_t)(n0 + r0) * K + k0;
        const size_t o1 = (size_t)(n0 + r1) * K + k0;
        gload16(Bhig + o0 + c0e, dB0);
        gload16(Bhig + o1 + c1e, dB1);
        gload16(Blog + o0 + c0e, dBl0);
        gload16(Blog + o1 + c1e, dBl1);
      }
      __syncthreads();   // drains vmcnt(0): tile staged

      if constexpr (MODE == 0) {
        const int t = k0 >> 8;
        int zr = -1;
        if (t == 0 && (m0 & 4095) == 0) zr = 0;
        if (t == 2 && (m0 & 4095) == 3968) zr = 127;
        if (zr >= 0) {
          if (tid < 8) {
            char* buf = (tid < 4) ? sAhi : sAlo;
            *(s16x8*)(buf + zr * 64 + (tid & 3) * 16) = s16x8{0,0,0,0,0,0,0,0};
          }
          __syncthreads();
        }
      }

      s16x8 Af[4], Al[4], Bf[4], Bl[4];
      #pragma unroll
      for (int i = 0; i < 4; ++i) {
        const int off = (wr * 64 + i * 16 + fr) * 64 + ((kc * 16) ^ fsw);
        Af[i] = *(const s16x8*)(sAhi + off);
        Al[i] = *(const s16x8*)(sAlo + off);
      }
      #pragma unroll
      for (int j = 0; j < 4; ++j) {
        const int off = (wc * 64 + j * 16 + fr) * 64 + ((kc * 16) ^ fsw);
        Bf[j] = *(const s16x8*)(sBhi + off);
        Bl[j] = *(const s16x8*)(sBlo + off);
      }
      #pragma unroll
      for (int i = 0; i < 4; ++i)
        #pragma unroll
        for (int j = 0; j < 4; ++j) {
          acc[i][j] = __builtin_amdgcn_mfma_f32_16x16x32_bf16(Af[i], Bf[j], acc[i][j], 0, 0, 0);
          acc[i][j] = __builtin_amdgcn_mfma_f32_16x16x32_bf16(Af[i], Bl[j], acc[i][j], 0, 0, 0);
          acc[i][j] = __builtin_amdgcn_mfma_f32_16x16x32_bf16(Al[i], Bf[j], acc[i][j], 0, 0, 0);
        }
    }
  } else {
    // double-buffered loop (plain modes): buffer p at {p*16384, p*16384+8192}
    auto stagep = [&](int k0, int par) {
      char* const bA = smem + par * 16384;
      char* const bB = bA + 8192;
      const size_t o0 = (size_t)(m0 + r0) * K + k0;
      const size_t o1 = (size_t)(m0 + r1) * K + k0;
      gload16(Ahi + o0 + c0e, bA + seg0 * 1024);
      gload16(Ahi + o1 + c1e, bA + seg0 * 1024 + 1024);
      const size_t b0 = (size_t)(n0 + r0) * K + k0;
      const size_t b1 = (size_t)(n0 + r1) * K + k0;
      gload16(Bhig + b0 + c0e, bB + seg0 * 1024);
      gload16(Bhig + b1 + c1e, bB + seg0 * 1024 + 1024);
    };
    stagep(0, 0);
    __syncthreads();                 // tile 0 landed
    for (int k0 = 0; k0 < K; k0 += 32) {
      const int cur = (k0 >> 5) & 1;
      if (k0 + 32 < K) stagep(k0 + 32, cur ^ 1);   // next tile streams in
      const char* bA = smem + cur * 16384;
      const char* bB = bA + 8192;
      s16x8 Af[4], Bf[4];
      #pragma unroll
      for (int i = 0; i < 4; ++i) {
        const int off = (wr * 64 + i * 16 + fr) * 64 + ((kc * 16) ^ fsw);
        Af[i] = *(const s16x8*)(bA + off);
      }
      #pragma unroll
      for (int j = 0; j < 4; ++j) {
        const int off = (wc * 64 + j * 16 + fr) * 64 + ((kc * 16) ^ fsw);
        Bf[j] = *(const s16x8*)(bB + off);
      }
      #pragma unroll
      for (int i = 0; i < 4; ++i)
        #pragma unroll
        for (int j = 0; j < 4; ++j)
          acc[i][j] = __builtin_amdgcn_mfma_f32_16x16x32_bf16(Af[i], Bf[j], acc[i][j], 0, 0, 0);
      __syncthreads();   // drains next-tile DMAs + WAR for buffer reuse
    }
  }

  // ---- epilogue ----
  if constexpr (MODE == 2) {
    #pragma unroll
    for (int i = 0; i < 4; ++i)
      #pragma unroll
      for (int j2 = 0; j2 < 2; ++j2) {
        const int col0 = n0 + wc * 64 + j2 * 16 + fr;
        const int jr = col0 & 31;
        const float b0 = bias[col0], b1 = bias[col0 + 32];
        #pragma unroll
        for (int rr = 0; rr < 4; ++rr) {
          const int row = m0 + wr * 64 + i * 16 + kc * 4 + rr;
          float v0 = acc[i][j2][rr] + b0;
          float v1 = acc[i][j2 + 2][rr] + b1;
          if (z < 2) {
            const float2 cs = tab[((row & 4095) << 5) | jr];
            const float rr0 = v0 * cs.x - v1 * cs.y;
            const float rr1 = v1 * cs.x + v0 * cs.y;
            v0 = rr0; v1 = rr1;
          }
          C1[(size_t)row * N + col0] = f2bf(v0);
          C1[(size_t)row * N + col0 + 32] = f2bf(v1);
        }
      }
  } else {
    #pragma unroll
    for (int i = 0; i < 4; ++i)
      #pragma unroll
      for (int j = 0; j < 4; ++j) {
        const int col = n0 + wc * 64 + j * 16 + fr;
        #pragma unroll
        for (int rr = 0; rr < 4; ++rr) {
          const int row = m0 + wr * 64 + i * 16 + kc * 4 + rr;
          const float v = acc[i][j][rr];
          if constexpr (MODE == 0) {
            const float hv = v + bias[col];
            const unsigned short hh = f2bf(hv);
            C1[(size_t)row * N + col] = hh;
            C2[(size_t)row * N + col] = f2bf(hv - bf2f(hh));
          } else if constexpr (MODE == 1) {
            const int g = col >> 8;
            const float sg = (g == 0) ? 1.0f : ((g == 1) ? 1.41421356237309515f : 2.0f);
            const float zc = cosf(v * sg + bias[col]) * 0.08838834764831845f;
            C1[(size_t)row * N + col] = f2bf(zc);
          } else {
            Cf[(size_t)row * N + col] = v + bias[col];
          }
        }
      }
  }
}

// ======================== FAVOR-K (MFMA, single-term) =======================
__global__ __launch_bounds__(512) void favor_k_mfma(
    const unsigned short* __restrict__ kny, const float* __restrict__ knorm,
    const unsigned short* __restrict__ oThi,
    const unsigned short* __restrict__ VT, float* __restrict__ KVp)
{
  const int bid = blockIdx.x;
  const int bh = bid >> 3, chunk = bid & 7;
  const int b = bh >> 4, h = bh & 15;
  const int s0 = chunk * 512;
  const int tid = threadIdx.x, lane = tid & 63, wid = tid >> 6;
  const int fr = lane & 15, kc = lane >> 4;
  const int m0w = wid * 32;

  __shared__ unsigned short P[256][40];
  __shared__ float T[8][32][84];

  s16x8 whi[2][2];
  #pragma unroll
  for (int c = 0; c < 2; ++c)
    #pragma unroll
    for (int ks = 0; ks < 2; ++ks)
      whi[c][ks] = *(const s16x8*)(oThi + (size_t)(m0w + c * 16 + fr) * 64 + ks * 32 + kc * 8);

  f32x4 acc2[2][5];
  #pragma unroll
  for (int i = 0; i < 2; ++i)
    #pragma unroll
    for (int j = 0; j < 5; ++j) acc2[i][j] = f32x4{0.f, 0.f, 0.f, 0.f};

  for (int st = 0; st < 512; st += 32) {
    s16x8 a1[2][2];
    float nrm[2];
    #pragma unroll
    for (int r = 0; r < 2; ++r) {
      const size_t kidx = (size_t)(b * 4096 + s0 + st + r * 16 + fr) * 16 + h;
      a1[r][0] = *(const s16x8*)(kny + kidx * 64 + kc * 8);
      a1[r][1] = *(const s16x8*)(kny + kidx * 64 + 32 + kc * 8);
      nrm[r] = knorm[kidx];
    }
    __syncthreads();
    #pragma unroll
    for (int r = 0; r < 2; ++r)
      #pragma unroll
      for (int c = 0; c < 2; ++c) {
        f32x4 s1 = f32x4{0.f, 0.f, 0.f, 0.f};
        s1 = __builtin_amdgcn_mfma_f32_16x16x32_bf16(a1[r][0], whi[c][0], s1, 0, 0, 0);
        s1 = __builtin_amdgcn_mfma_f32_16x16x32_bf16(a1[r][1], whi[c][1], s1, 0, 0, 0);
        #pragma unroll
        for (int reg = 0; reg < 4; ++reg) {
          const int sl = kc * 4 + reg;
          const float nn = __shfl(nrm[r], sl);
          const float p = __expf(s1[reg] - nn - 2.772588722239781f);
          P[m0w + c * 16 + fr][r * 16 + sl] = f2bf(p);
        }
      }
    __syncthreads();
    s16x8 b2[5];
    #pragma unroll
    for (int nf = 0; nf < 5; ++nf)
      b2[nf] = *(const s16x8*)(VT + ((size_t)bh * 80 + nf * 16 + fr) * 4096 +
                               s0 + st + kc * 8);
    #pragma unroll
    for (int mf = 0; mf < 2; ++mf) {
      const s16x8 a2 = *(const s16x8*)&P[m0w + mf * 16 + fr][kc * 8];
      #pragma unroll
      for (int nf = 0; nf < 5; ++nf)
        acc2[mf][nf] = __builtin_amdgcn_mfma_f32_16x16x32_bf16(a2, b2[nf], acc2[mf][nf], 0, 0, 0);
    }
  }
  #pragma unroll
  for (int mf = 0; mf < 2; ++mf)
    #pragma unroll
    for (int nf = 0; nf < 5; ++nf)
      #pragma unroll
      for (int reg = 0; reg < 4; ++reg)
        T[wid][mf * 16 + kc * 4 + reg][nf * 16 + fr] = acc2[mf][nf][reg];
  __syncthreads();
  #pragma unroll
  for (int i = 0; i < 40; ++i) {
    const int flat = i * 64 + lane;
    const int n = flat >> 5, ml = flat & 31;
    KVp[((size_t)bid * 80 + n) * 256 + m0w + ml] = T[wid][ml][n];
  }
}

// ======================== reduce KVp -> KVXT bf16 (widened) =================
__global__ __launch_bounds__(256) void reduce_kvxt_kernel(
    const float* __restrict__ KVp, unsigned short* __restrict__ KVXT)
{
  const int bh = blockIdx.x;
  const int n0 = blockIdx.y * 8;
  const int m = threadIdx.x;
  #pragma unroll
  for (int n = n0; n < n0 + 8; ++n) {
    float s = 0.f;
    #pragma unroll
    for (int c = 0; c < 8; ++c)
      s += KVp[((size_t)(bh * 8 + c) * 80 + n) * 256 + m];
    KVXT[((size_t)bh * 80 + n) * 256 + m] = f2bf(s);
  }
}

// ======================== FAVOR-Q (MFMA, bf16 Q input) ======================
__global__ __launch_bounds__(512) void favor_q_mfma(
    const unsigned short* __restrict__ Q, const unsigned short* __restrict__ oThi,
    const unsigned short* __restrict__ KVXT, unsigned short* __restrict__ O)
{
  const int bid = blockIdx.x;
  const int bh = bid >> 4, chunk = bid & 15;
  const int b = bh >> 4, h = bh & 15;
  const int s0 = chunk * 256;
  const int tid = threadIdx.x, lane = tid & 63, wid = tid >> 6;
  const int fr = lane & 15, kc = lane >> 4;
  const int ws0 = s0 + wid * 32;

  __shared__ unsigned short KX[80][264];
  __shared__ unsigned short P[8][32][66];

  for (int i = tid; i < 80 * 256; i += 512)
    KX[i >> 8][i & 255] = KVXT[(size_t)bh * 80 * 256 + i];
  __syncthreads();

  s16x8 ahi[2][2];
  float nrm[2];
  #pragma unroll
  for (int r = 0; r < 2; ++r) {
    float part = 0.f;
    const unsigned short* ap = Q + ((size_t)(b * 4096 + ws0 + r * 16 + fr)) * 1024 + h * 64;
    #pragma unroll
    for (int ks = 0; ks < 2; ++ks) {
      ahi[r][ks] = *(const s16x8*)(ap + ks * 32 + kc * 8);
      #pragma unroll
      for (int u = 0; u < 8; ++u) {
        const float v = bf2f((unsigned short)ahi[r][ks][u]);
        part = fmaf(v, v, part);
      }
    }
    part += __shfl_xor(part, 16);
    part += __shfl_xor(part, 32);
    nrm[r] = 0.5f * part;
  }

  f32x4 acc2[2][5];
  #pragma unroll
  for (int i = 0; i < 2; ++i)
    #pragma unroll
    for (int j = 0; j < 5; ++j) acc2[i][j] = f32x4{0.f, 0.f, 0.f, 0.f};

  for (int mc = 0; mc < 4; ++mc) {
    __syncthreads();
    #pragma unroll
    for (int r = 0; r < 2; ++r)
      #pragma unroll
      for (int c = 0; c < 4; ++c) {
        f32x4 s1 = f32x4{0.f, 0.f, 0.f, 0.f};
        #pragma unroll
        for (int ks = 0; ks < 2; ++ks) {
          const size_t off = (size_t)(mc * 64 + c * 16 + fr) * 64 + ks * 32 + kc * 8;
          const s16x8 bh1 = *(const s16x8*)(oThi + off);
          s1 = __builtin_amdgcn_mfma_f32_16x16x32_bf16(ahi[r][ks], bh1, s1, 0, 0, 0);
        }
        #pragma unroll
        for (int reg = 0; reg < 4; ++reg) {
          const int sl = kc * 4 + reg;
          const float nn = __shfl(nrm[r], sl);
          const float p = __expf(s1[reg] - nn - 2.772588722239781f);
          P[wid][r * 16 + sl][c * 16 + fr] = f2bf(p);
        }
      }
    __syncthreads();
    #pragma unroll
    for (int ks2 = 0; ks2 < 2; ++ks2) {
      s16x8 b2[5];
      #pragma unroll
      for (int nf = 0; nf < 5; ++nf)
        b2[nf] = *(const s16x8*)&KX[nf * 16 + fr][mc * 64 + ks2 * 32 + kc * 8];
      #pragma unroll
      for (int r = 0; r < 2; ++r) {
        const s16x8 a2 = *(const s16x8*)&P[wid][r * 16 + fr][ks2 * 32 + kc * 8];
        #pragma unroll
        for (int nf = 0; nf < 5; ++nf)
          acc2[r][nf] = __builtin_amdgcn_mfma_f32_16x16x32_bf16(a2, b2[nf], acc2[r][nf], 0, 0, 0);
      }
    }
  }
  #pragma unroll
  for (int r = 0; r < 2; ++r)
    #pragma unroll
    for (int reg = 0; reg < 4; ++reg) {
      const int s = ws0 + r * 16 + kc * 4 + reg;
      const float dv = __shfl(acc2[r][4][reg], lane & 48) + 1e-6f;
      #pragma unroll
      for (int nf = 0; nf < 4; ++nf)
        O[(size_t)(b * 4096 + s) * 1024 + h * 64 + nf * 16 + fr] =
            f2bf(acc2[r][nf][reg] / dv);
    }
}

// ======================== launcher ==========================================
extern "C" void kernel_launch(void* const* d_in, const int* in_sizes, int n_in,
                              void* d_out, int out_size, void* d_ws, size_t ws_size,
                              hipStream_t stream)
{
  const float* x      = (const float*)d_in[0];
  const float* conv_k = (const float*)d_in[1];
  const float* conv_b = (const float*)d_in[2];
  const float* rff_w  = (const float*)d_in[3];
  const float* rff_b  = (const float*)d_in[4];
  const float* proj_w = (const float*)d_in[5];
  const float* proj_b = (const float*)d_in[6];
  const float* omega  = (const float*)d_in[7];
  const float* lm     = (const float*)d_in[8];
  const float* out_w  = (const float*)d_in[9];
  const float* out_b  = (const float*)d_in[10];

  char* wsb = (char*)d_ws;
  size_t o = 0;
  auto alloc = [&](size_t bytes) {
    char* p = wsb + o;
    o = (o + bytes + 255) & ~(size_t)255;
    return p;
  };
  // --- region A: persistent (weights/tables)
  unsigned short* Wc_hi = (unsigned short*)alloc(4718592);
  unsigned short* Wc_lo = (unsigned short*)alloc(4718592);
  unsigned short* Wr_hi = (unsigned short*)alloc(4718592);
  unsigned short* Wr_lo = (unsigned short*)alloc(4718592);
  unsigned short* Wp    = (unsigned short*)alloc(4718592);
  unsigned short* Wo    = (unsigned short*)alloc(2097152);
  unsigned short* oThi  = (unsigned short*)alloc(32768);
  float2* tab           = (float2*)alloc(1048576);
  // --- region B: xhi/xlo -> feats -> {VT, Obf, KVXT}
  char* RB = alloc(41943040);
  unsigned short* xhi   = (unsigned short*)RB;
  unsigned short* xlo   = (unsigned short*)(RB + 16777216);
  unsigned short* feats = (unsigned short*)RB;
  unsigned short* VT    = (unsigned short*)RB;
  unsigned short* Obf   = (unsigned short*)(RB + 20971520);
  unsigned short* KVXT  = (unsigned short*)(RB + 37748736);
  // --- region C: h hi/lo (3x) -> QKV bf16 (3x)
  char* RC = alloc(100663296);
  unsigned short* hhi   = (unsigned short*)RC;
  unsigned short* hlo   = (unsigned short*)(RC + 50331648);
  unsigned short* QKV   = (unsigned short*)RC;            // 48 MB bf16
  // --- region E: kny bf16 + knorm + KVp
  char* RE = alloc(33554432);
  unsigned short* knyb  = (unsigned short*)RE;
  float* knorm          = (float*)(RE + 16777216);
  float* KVp = (float*)alloc(20971520);
  (void)ws_size;

  dim3 blk(256);
  prep_all_kernel<<<6656, blk, 0, stream>>>(
      x, xhi, xlo, omega, oThi, tab,
      conv_k, rff_w, proj_w, out_w,
      Wc_hi, Wc_lo, Wr_hi, Wr_lo, Wp, Wo);

  gemm_mfma<0><<<dim3(8, 64, 3), blk, 0, stream>>>(
      xhi, xlo, Wc_hi, Wc_lo, conv_b, nullptr,
      nullptr, hhi, hlo, 8192, 1024, 768);
  gemm_mfma<1><<<dim3(6, 64, 3), blk, 0, stream>>>(
      hhi, hlo, Wr_hi, Wr_lo, rff_b, nullptr,
      nullptr, feats, nullptr, 8192, 768, 1024);
  gemm_mfma<2><<<dim3(8, 64, 3), blk, 0, stream>>>(
      feats, nullptr, Wp, nullptr, proj_b, tab,
      nullptr, QKV, nullptr, 8192, 1024, 768);

  unsigned short* Qb = QKV;
  unsigned short* Kb = QKV + 8388608;
  unsigned short* Vb = QKV + 16777216;
  vtny_kernel<<<2560, blk, 0, stream>>>(Vb, VT, Kb, lm, knyb, knorm);
  favor_k_mfma<<<256, dim3(512), 0, stream>>>(knyb, knorm, oThi, VT, KVp);
  reduce_kvxt_kernel<<<dim3(32, 10), blk, 0, stream>>>(KVp, KVXT);
  favor_q_mfma<<<512, dim3(512), 0, stream>>>(Qb, oThi, KVXT, Obf);
  gemm_mfma<3><<<dim3(8, 64, 1), blk, 0, stream>>>(
      Obf, nullptr, Wo, nullptr, out_b, nullptr,
      (float*)d_out, nullptr, nullptr, 8192, 1024, 1024);
}